// Round 7
// baseline (677.350 us; speedup 1.0000x reference)
//
#include <hip/hip_runtime.h>
#include <math.h>

#define MIN_NORM 1e-15f

// B=32, S=256, V=30000, L=1024, H=4, D=64

// ---- fast scalar helpers ----
__device__ __forceinline__ float frcp(float x){ return __builtin_amdgcn_rcpf(x); }
__device__ __forceinline__ float fsqrt(float x){ return __builtin_amdgcn_sqrtf(x); }
__device__ __forceinline__ float fast_atanh(float x){        // x in [0, 1-1e-7]
  return 0.5f * __logf((1.f + x) * frcp(1.f - x));
}
__device__ __forceinline__ float fast_tanh(float y){         // y >= 0
  float e = __expf(-2.f * y);
  return (1.f - e) * frcp(1.f + e);
}
__device__ __forceinline__ float rdlane(float v, int l){     // runtime lane idx OK
  return __int_as_float(__builtin_amdgcn_readlane(__float_as_int(v), l));
}

// ---- DPP wave64 sum reductions (result broadcast via readlane 63) ----
#define DPPADD(v, ctrl) \
  v += __int_as_float(__builtin_amdgcn_update_dpp(0, __float_as_int(v), ctrl, 0xf, 0xf, false));

__device__ __forceinline__ float wred_b(float v){
  DPPADD(v,0x111) DPPADD(v,0x112) DPPADD(v,0x114) DPPADD(v,0x118)
  DPPADD(v,0x142) DPPADD(v,0x143)
  return __int_as_float(__builtin_amdgcn_readlane(__float_as_int(v), 63));
}
__device__ __forceinline__ void wred3_b(float& v0, float& v1, float& v2){
  DPPADD(v0,0x111) DPPADD(v1,0x111) DPPADD(v2,0x111)
  DPPADD(v0,0x112) DPPADD(v1,0x112) DPPADD(v2,0x112)
  DPPADD(v0,0x114) DPPADD(v1,0x114) DPPADD(v2,0x114)
  DPPADD(v0,0x118) DPPADD(v1,0x118) DPPADD(v2,0x118)
  DPPADD(v0,0x142) DPPADD(v1,0x142) DPPADD(v2,0x142)
  DPPADD(v0,0x143) DPPADD(v1,0x143) DPPADD(v2,0x143)
  v0 = __int_as_float(__builtin_amdgcn_readlane(__float_as_int(v0), 63));
  v1 = __int_as_float(__builtin_amdgcn_readlane(__float_as_int(v1), 63));
  v2 = __int_as_float(__builtin_amdgcn_readlane(__float_as_int(v2), 63));
}
// 6 interleaved reductions (two chains' {m.m, m.u, m.b}) in one DPP tree
__device__ __forceinline__ void wred6_b(float& v0, float& v1, float& v2,
                                        float& v3, float& v4, float& v5){
  DPPADD(v0,0x111) DPPADD(v1,0x111) DPPADD(v2,0x111) DPPADD(v3,0x111) DPPADD(v4,0x111) DPPADD(v5,0x111)
  DPPADD(v0,0x112) DPPADD(v1,0x112) DPPADD(v2,0x112) DPPADD(v3,0x112) DPPADD(v4,0x112) DPPADD(v5,0x112)
  DPPADD(v0,0x114) DPPADD(v1,0x114) DPPADD(v2,0x114) DPPADD(v3,0x114) DPPADD(v4,0x114) DPPADD(v5,0x114)
  DPPADD(v0,0x118) DPPADD(v1,0x118) DPPADD(v2,0x118) DPPADD(v3,0x118) DPPADD(v4,0x118) DPPADD(v5,0x118)
  DPPADD(v0,0x142) DPPADD(v1,0x142) DPPADD(v2,0x142) DPPADD(v3,0x142) DPPADD(v4,0x142) DPPADD(v5,0x142)
  DPPADD(v0,0x143) DPPADD(v1,0x143) DPPADD(v2,0x143) DPPADD(v3,0x143) DPPADD(v4,0x143) DPPADD(v5,0x143)
  v0 = __int_as_float(__builtin_amdgcn_readlane(__float_as_int(v0), 63));
  v1 = __int_as_float(__builtin_amdgcn_readlane(__float_as_int(v1), 63));
  v2 = __int_as_float(__builtin_amdgcn_readlane(__float_as_int(v2), 63));
  v3 = __int_as_float(__builtin_amdgcn_readlane(__float_as_int(v3), 63));
  v4 = __int_as_float(__builtin_amdgcn_readlane(__float_as_int(v4), 63));
  v5 = __int_as_float(__builtin_amdgcn_readlane(__float_as_int(v5), 63));
}

__device__ __forceinline__ float wred(float v){   // shfl version (TLP-rich kernels)
#pragma unroll
  for(int o=32;o;o>>=1) v += __shfl_xor(v, o, 64);
  return v;
}

#define LDS_FENCE() asm volatile("s_waitcnt lgkmcnt(0)" ::: "memory")

// 64-dot-product: RES = sum_j WROW[j]*HSARR[j]; 8 accumulators for ILP.
#define MATVEC64(RES, WROW, HSARR) {                                     \
  float a0=0.f,a1=0.f,a2=0.f,a3=0.f,a4=0.f,a5=0.f,a6=0.f,a7=0.f;         \
  _Pragma("unroll")                                                      \
  for(int j=0;j<64;j+=8){                                                \
    float4 h4 = *(const float4*)(&(HSARR)[j]);                           \
    float4 h5 = *(const float4*)(&(HSARR)[j+4]);                         \
    a0 = fmaf((WROW)[j  ], h4.x, a0); a1 = fmaf((WROW)[j+1], h4.y, a1);  \
    a2 = fmaf((WROW)[j+2], h4.z, a2); a3 = fmaf((WROW)[j+3], h4.w, a3);  \
    a4 = fmaf((WROW)[j+4], h5.x, a4); a5 = fmaf((WROW)[j+5], h5.y, a5);  \
    a6 = fmaf((WROW)[j+6], h5.z, a6); a7 = fmaf((WROW)[j+7], h5.w, a7);  \
  }                                                                      \
  RES = ((a0+a1)+(a2+a3)) + ((a4+a5)+(a6+a7));                           \
}

// ---- kernel 1: ux = mobius_matvec(U, wemb[x]); wux = W.ux; uxn2=||ux||^2; uxb=ux.b ----
__global__ __launch_bounds__(256) void k_ux(const int* __restrict__ x,
    const float* __restrict__ wemb, const float* __restrict__ U,
    const float* __restrict__ Wm, const float* __restrict__ bvec,
    float* __restrict__ ux, float* __restrict__ wux,
    float* __restrict__ uxn2, float* __restrict__ uxb){
  __shared__ __align__(16) float xs[4][64];
  const int wv = threadIdx.x >> 6, lane = threadIdx.x & 63;
  const int bid = blockIdx.x*4 + wv;   // (b*S+s)*4 + h
  const int h = bid & 3;
  const int bs = bid >> 2;
  const int v = x[bs];
  float xi = wemb[(size_t)v*256 + h*64 + lane];
  const float bi = bvec[h*64 + lane];
  xs[wv][lane] = xi;
  LDS_FENCE();
  float mx; MATVEC64(mx, U + h*4096 + lane*64, xs[wv]);
  float t0 = xi*xi, t1 = mx*mx, t2 = mx*bi;
  wred3_b(t0, t1, t2);         // t0=||x||^2, t1=||mx||^2, t2=mx.b
  float xn  = fmaxf(fsqrt(t0), MIN_NORM);
  float mxn = fmaxf(fsqrt(t1), MIN_NORM);
  float scale = fast_tanh(mxn*frcp(xn) * fast_atanh(fminf(xn, 1.f-1e-7f)));
  float sm = scale * frcp(mxn);
  float uxv = sm * mx;                    // mx==0 -> 0
  ux[(size_t)bid*64 + lane] = uxv;
  if(lane==0){
    uxn2[bid] = (t1 > 0.f) ? scale*scale : 0.f;
    uxb[bid]  = sm * t2;
  }
  // second matvec: wux = W . ux  (feeds k_rnn's m-space recurrence)
  xs[wv][lane] = uxv;                     // same-wave DS ops are in-order: safe reuse
  LDS_FENCE();
  float wuv; MATVEC64(wuv, Wm + h*4096 + lane*64, xs[wv]);
  wux[(size_t)bid*64 + lane] = wuv;
}

// ---- kernel 2: sequential Mobius RNN in m-space, TWO chains per wave ----
// Chains (2b0,h) and (2b0+1,h) share wrow/bi/bn2/wb. Their matvecs, DPP
// reductions and transcendental tails are independent -> the compiler
// interleaves them, filling each chain's latency stalls with the other's
// issue slots (round-6 diagnosis: active-SIMD VALUBusy ~60%, rest stalls).
__device__ __forceinline__ void mob_tail(float p0, float p1, float p2,
    float y2, float ub, float bn2v,
    float& hh, float& al, float& be, float& ga){
  float xn  = fmaxf(fsqrt(hh), MIN_NORM);
  float mxn = fmaxf(fsqrt(p0), MIN_NORM);
  float at  = fast_atanh(fminf(xn, 1.f-1e-7f));
  float scale = fast_tanh(mxn*frcp(xn)*at);
  float sm  = scale*frcp(mxn);
  float wx2 = (p0 > 0.f) ? scale*scale : 0.f;
  float xy  = sm*p1;
  float A   = 1.f + 2.f*xy + y2;
  float Bc  = 1.f - wx2;
  float iden = frcp(fmaxf(1.f + 2.f*xy + wx2*y2, MIN_NORM));
  float c1 = A*sm*iden, c2 = Bc*iden;
  float zz = (A*A*wx2 + 2.f*A*Bc*xy + Bc*Bc*y2)*iden*iden;
  float zb = (A*sm*p2 + Bc*ub)*iden;
  float A2 = 1.f + 2.f*zb + bn2v;
  float B2 = 1.f - zz;
  float iden2 = frcp(fmaxf(1.f + 2.f*zb + zz*bn2v, MIN_NORM));
  float e  = A2*iden2;
  ga = B2*iden2;
  al = e*c1; be = e*c2;
  hh = fmaxf(e*e*zz + 2.f*e*ga*zb + ga*ga*bn2v, 0.f);
}

#define RNN_STEP2(S, UA, WUA, Y2A, UBA, UBC, WUB, Y2B, UBB) {            \
  hsA[lane] = mA; hsB[lane] = mB;           /* broadcast both m_s */     \
  const float uA_ = UA, wuA_ = WUA, uB_ = UBC, wuB_ = WUB;               \
  const float y2a = (Y2A), uba = (UBA), y2b = (Y2B), ubb = (UBB);        \
  if((S) < 254){                            /* depth-2 prefetch */       \
    UA  = uxpA [(size_t)((S)+2)*256 + lane];                             \
    WUA = wuxpA[(size_t)((S)+2)*256 + lane];                             \
    UBC = uxpB [(size_t)((S)+2)*256 + lane];                             \
    WUB = wuxpB[(size_t)((S)+2)*256 + lane];                             \
  }                                                                      \
  float pa0 = mA*mA, pa1 = mA*uA_, pa2 = mA*bi;                          \
  float pb0 = mB*mB, pb1 = mB*uB_, pb2 = mB*bi;                          \
  wred6_b(pa0, pa1, pa2, pb0, pb1, pb2);    /* one tree, both chains */  \
  LDS_FENCE();                                                           \
  float rA; MATVEC64(rA, wrow, hsA);                                     \
  float rB; MATVEC64(rB, wrow, hsB);                                     \
  float alA, beA, gaA; mob_tail(pa0, pa1, pa2, y2a, uba, bn2v, hhA, alA, beA, gaA); \
  float alB, beB, gaB; mob_tail(pb0, pb1, pb2, y2b, ubb, bn2v, hhB, alB, beB, gaB); \
  encpA[(size_t)(S)*256 + lane] = fmaf(alA, mA, fmaf(beA, uA_, gaA*bi)); \
  encpB[(size_t)(S)*256 + lane] = fmaf(alB, mB, fmaf(beB, uB_, gaB*bi)); \
  mA = fmaf(alA, rA, fmaf(beA, wuA_, gaA*wb));                           \
  mB = fmaf(alB, rB, fmaf(beB, wuB_, gaB*wb));                           \
}

#define RNN_BLOCK2(BLK, Y2AR, UBAR, Y2BR, UBBR)                          \
  for(int i=0;i<64;i+=2){                                                \
    RNN_STEP2((BLK)*64+i,   uA0, wuA0, rdlane(Y2AR, i),   rdlane(UBAR, i),   \
                            uB0, wuB0, rdlane(Y2BR, i),   rdlane(UBBR, i));  \
    RNN_STEP2((BLK)*64+i+1, uA1, wuA1, rdlane(Y2AR, i+1), rdlane(UBAR, i+1), \
                            uB1, wuB1, rdlane(Y2BR, i+1), rdlane(UBBR, i+1));\
  }

__global__ __launch_bounds__(64) void k_rnn(const float* __restrict__ W,
    const float* __restrict__ bvec, const float* __restrict__ ux,
    const float* __restrict__ wux, const float* __restrict__ uxn2,
    const float* __restrict__ uxb, float* __restrict__ enc){
  const int h = blockIdx.x & 3, b0 = (blockIdx.x >> 2)*2;   // chains b0, b0+1
  const int lane = threadIdx.x;
  float wrow[64];
  const float* Wp = W + h*4096 + lane*64;
#pragma unroll
  for(int j=0;j<64;j+=4){
    float4 w4 = *(const float4*)(Wp + j);
    wrow[j]=w4.x; wrow[j+1]=w4.y; wrow[j+2]=w4.z; wrow[j+3]=w4.w;
  }
  const float bi = bvec[h*64 + lane];
  __shared__ __align__(16) float hsA[64], hsB[64];
  // preamble: bn2 = ||b||^2 and wb = W.b (shared by both chains)
  hsA[lane] = bi;
  const float bn2v = wred_b(bi*bi);
  LDS_FENCE();
  float wb; MATVEC64(wb, wrow, hsA);
  const float* uxpA   = ux   + (size_t)b0*65536 + h*64;   // + s*256 + lane
  const float* wuxpA  = wux  + (size_t)b0*65536 + h*64;
  const float* uxn2pA = uxn2 + (size_t)b0*1024  + h;      // + s*4
  const float* uxbpA  = uxb  + (size_t)b0*1024  + h;
  float* encpA        = enc  + (size_t)b0*65536 + h*64;
  const float* uxpB   = uxpA   + 65536;
  const float* wuxpB  = wuxpA  + 65536;
  const float* uxn2pB = uxn2pA + 1024;
  const float* uxbpB  = uxbpA  + 1024;
  float* encpB        = encpA  + 65536;
  // scalar tables -> VGPRs: lane ℓ of reg blk holds step blk*64+ℓ (no SMEM in loop)
  float y2A0 = uxn2pA[(      lane)*4], ubA0 = uxbpA[(      lane)*4];
  float y2A1 = uxn2pA[( 64 + lane)*4], ubA1 = uxbpA[( 64 + lane)*4];
  float y2A2 = uxn2pA[(128 + lane)*4], ubA2 = uxbpA[(128 + lane)*4];
  float y2A3 = uxn2pA[(192 + lane)*4], ubA3 = uxbpA[(192 + lane)*4];
  float y2B0 = uxn2pB[(      lane)*4], ubB0 = uxbpB[(      lane)*4];
  float y2B1 = uxn2pB[( 64 + lane)*4], ubB1 = uxbpB[( 64 + lane)*4];
  float y2B2 = uxn2pB[(128 + lane)*4], ubB2 = uxbpB[(128 + lane)*4];
  float y2B3 = uxn2pB[(192 + lane)*4], ubB3 = uxbpB[(192 + lane)*4];
  // prefetch slots: steps s (slot0) and s+1 (slot1), per chain
  float uA0 = uxpA[lane],       wuA0 = wuxpA[lane];
  float uA1 = uxpA[256+lane],   wuA1 = wuxpA[256+lane];
  float uB0 = uxpB[lane],       wuB0 = wuxpB[lane];
  float uB1 = uxpB[256+lane],   wuB1 = wuxpB[256+lane];
  float mA = 0.f, hhA = 0.f, mB = 0.f, hhB = 0.f;   // h_0 = 0 -> m_0 = 0
  RNN_BLOCK2(0, y2A0, ubA0, y2B0, ubB0)
  RNN_BLOCK2(1, y2A1, ubA1, y2B1, ubB1)
  RNN_BLOCK2(2, y2A2, ubA2, y2B2, ubB2)
  RNN_BLOCK2(3, y2A3, ubA3, y2B3, ubB3)
}

// ---- row squared-norms: src is [nrows][64] ----
__global__ __launch_bounds__(256) void k_norm2(const float* __restrict__ src,
    float* __restrict__ dst, int nrows){
  const int row = blockIdx.x*4 + (threadIdx.x>>6);
  const int lane = threadIdx.x & 63;
  if(row >= nrows) return;
  float v = src[(size_t)row*64 + lane];
  float n2 = wred(v*v);
  if(lane==0) dst[row] = n2;
}

// acosh(1+y) = log(1 + y + sqrt(y*(2+y))) — cancellation-free, ~13 VALU ops
// vs libm acoshf's ~350-400 (measured: acoshf was 85% of k_dist's VALU issue).
__device__ __forceinline__ float pdist(float dot, float a, float lb){
  float c2  = fmaxf(a + lb - 2.f*dot, 0.f);
  float iden = frcp(fmaxf((1.f-a)*(1.f-lb), MIN_NORM));
  float y   = fmaxf(2.f*c2*iden, 1e-7f);     // == max(arg,1+1e-7) semantics
  return __logf(1.f + y + fsqrt(y*(2.f+y)));
}

// ---- kernel 3: interaction[b,l,s] = sum_h poinc_dist(enc[b,s,h],lab[l,h]) ----
#define LP 68  // padded LDS stride (64 + 4), keeps b128 16B-aligned, kills conflicts
__global__ __launch_bounds__(256) void k_dist(const float* __restrict__ enc,
    const float* __restrict__ lab, const float* __restrict__ an,
    const float* __restrict__ lbn, float* __restrict__ inter){
  __shared__ __align__(16) float eT[4*16*LP];
  __shared__ __align__(16) float lT[4*16*LP];
  const int bs0 = blockIdx.x*64, l0 = blockIdx.y*64;
  const int t = threadIdx.x;
  const int tr = t>>4, tc = t&15;
  const int ldr = t>>2, ldp = t&3;
  float acc[4][4][4];
#pragma unroll
  for(int h=0;h<4;h++)
#pragma unroll
    for(int i=0;i<4;i++)
#pragma unroll
      for(int j=0;j<4;j++) acc[h][i][j]=0.f;

  for(int c=0;c<4;c++){
    if(c) __syncthreads();
#pragma unroll
    for(int h=0;h<4;h++){
      float4 ev = *(const float4*)&enc[(size_t)(bs0+ldr)*256 + h*64 + c*16 + ldp*4];
      float4 lv = *(const float4*)&lab[(size_t)(l0 +ldr)*256 + h*64 + c*16 + ldp*4];
      int base = (h*16 + ldp*4)*LP + ldr;
      eT[base     ] = ev.x; eT[base+  LP] = ev.y; eT[base+2*LP] = ev.z; eT[base+3*LP] = ev.w;
      lT[base     ] = lv.x; lT[base+  LP] = lv.y; lT[base+2*LP] = lv.z; lT[base+3*LP] = lv.w;
    }
    __syncthreads();
#pragma unroll
    for(int dd=0;dd<16;dd++){
#pragma unroll
      for(int h=0;h<4;h++){
        float4 e4 = *(const float4*)&eT[(h*16+dd)*LP + tr*4];
        float4 l4 = *(const float4*)&lT[(h*16+dd)*LP + tc*4];
        float ee[4] = {e4.x,e4.y,e4.z,e4.w};
        float ll[4] = {l4.x,l4.y,l4.z,l4.w};
#pragma unroll
        for(int i=0;i<4;i++)
#pragma unroll
          for(int j=0;j<4;j++)
            acc[h][i][j] = fmaf(ee[i], ll[j], acc[h][i][j]);
      }
    }
  }
  const int b = bs0 >> 8;
#pragma unroll
  for(int i=0;i<4;i++){
    const int bs = bs0 + tr*4 + i;
    const int s  = bs & 255;
    float4 ah = *(const float4*)&an[(size_t)bs*4];
#pragma unroll
    for(int j=0;j<4;j++){
      const int l = l0 + tc*4 + j;
      float4 lb = *(const float4*)&lbn[(size_t)l*4];
      float d = pdist(acc[0][i][j], ah.x, lb.x)
              + pdist(acc[1][i][j], ah.y, lb.y)
              + pdist(acc[2][i][j], ah.z, lb.z)
              + pdist(acc[3][i][j], ah.w, lb.w);
      inter[((size_t)b*1024 + l)*256 + s] = d;
    }
  }
}

// ---- kernel 4: out[b,l] = w2 . relu(w1 @ inter[b,l,:] + b1) + b2 ----
__global__ __launch_bounds__(256) void k_mlp(const float* __restrict__ inter,
    const float* __restrict__ w1, const float* __restrict__ b1,
    const float* __restrict__ w2, const float* __restrict__ b2,
    float* __restrict__ out){
  __shared__ __align__(16) float rows[32*256];
  __shared__ float part[4][16];
  const int b  = blockIdx.x >> 5;
  const int l0 = (blockIdx.x & 31)*32;
  const int t = threadIdx.x;
  const float* ip = inter + ((size_t)b*1024 + l0)*256;
#pragma unroll
  for(int k=0;k<8;k++){
    int idx = k*1024 + t*4;
    *(float4*)&rows[idx] = *(const float4*)&ip[idx];
  }
  __syncthreads();
  const int f = t & 127, g = t >> 7;
  float acc[16];
#pragma unroll
  for(int li=0;li<16;li++) acc[li]=0.f;
  const float* wp = w1 + (size_t)f*256;
  for(int s=0;s<256;s+=4){
    float4 w4 = *(const float4*)&wp[s];
#pragma unroll
    for(int li=0;li<16;li++){
      float4 r4 = *(const float4*)&rows[(g*16+li)*256 + s];
      acc[li] = fmaf(r4.w, w4.w, fmaf(r4.z, w4.z, fmaf(r4.y, w4.y, fmaf(r4.x, w4.x, acc[li]))));
    }
  }
  const float bb1 = b1[f], ww2 = w2[f];
  const int wave = t>>6, lane = t&63;
#pragma unroll
  for(int li=0;li<16;li++){
    float vv = fmaxf(acc[li] + bb1, 0.f) * ww2;
    vv = wred(vv);
    if(lane==0) part[wave][li] = vv;
  }
  __syncthreads();
  if(t < 32){
    int g2 = t>>4, li = t&15;
    out[(size_t)b*1024 + l0 + g2*16 + li] = part[2*g2][li] + part[2*g2+1][li] + b2[0];
  }
}

extern "C" void kernel_launch(void* const* d_in, const int* in_sizes, int n_in,
                              void* d_out, int out_size, void* d_ws, size_t ws_size,
                              hipStream_t stream){
  const int*   x    = (const int*)d_in[0];
  const float* wemb = (const float*)d_in[1];
  const float* lab  = (const float*)d_in[2];
  const float* W    = (const float*)d_in[3];
  const float* U    = (const float*)d_in[4];
  const float* bv   = (const float*)d_in[5];
  const float* w1   = (const float*)d_in[6];
  const float* b1   = (const float*)d_in[7];
  const float* w2   = (const float*)d_in[8];
  const float* b2   = (const float*)d_in[9];
  float* out = (float*)d_out;

  float* ws    = (float*)d_ws;
  float* enc   = ws;                      // 2,097,152 f  [B*S*H][64]
  float* an    = enc + 2097152;           //    32,768 f  [B*S*H]
  float* lbn   = an  + 32768;             //     4,096 f  [L*H]
  float* ux    = lbn + 4096;              // 2,097,152 f  (dead after k_rnn)
  float* uxn2  = ux  + 2097152;           //    32,768 f
  float* uxb   = uxn2 + 32768;            //    32,768 f
  float* wux   = uxb + 32768;             // 2,097,152 f  (dead after k_rnn)
  float* inter = lbn + 4096;              // 8,388,608 f  [B][L][S] (overlaps ux..wux)
  // peak ws use: 2134016 + 8388608 floats ≈ 42.1 MB (unchanged)

  k_ux   <<<8192, 256, 0, stream>>>(x, wemb, U, W, bv, ux, wux, uxn2, uxb);
  k_norm2<<<1024, 256, 0, stream>>>(lab, lbn, 4096);
  k_rnn  <<<64,    64, 0, stream>>>(W, bv, ux, wux, uxn2, uxb, enc);
  k_norm2<<<8192, 256, 0, stream>>>(enc, an, 32768);
  dim3 g3(128, 16);
  k_dist <<<g3,   256, 0, stream>>>(enc, lab, an, lbn, inter);
  k_mlp  <<<1024, 256, 0, stream>>>(inter, w1, b1, w2, b2, out);
}

// Round 8
// 469.019 us; speedup vs baseline: 1.4442x; 1.4442x over previous
//
#include <hip/hip_runtime.h>
#include <math.h>

#define MIN_NORM 1e-15f

// B=32, S=256, V=30000, L=1024, H=4, D=64

// ---- fast scalar helpers ----
__device__ __forceinline__ float frcp(float x){ return __builtin_amdgcn_rcpf(x); }
__device__ __forceinline__ float fsqrt(float x){ return __builtin_amdgcn_sqrtf(x); }
__device__ __forceinline__ float fast_atanh(float x){        // x in [0, 1-1e-7]
  return 0.5f * __logf((1.f + x) * frcp(1.f - x));
}
__device__ __forceinline__ float fast_tanh(float y){         // y >= 0
  float e = __expf(-2.f * y);
  return (1.f - e) * frcp(1.f + e);
}
__device__ __forceinline__ float rdlane(float v, int l){     // imm/uniform lane idx
  return __int_as_float(__builtin_amdgcn_readlane(__float_as_int(v), l));
}

// ---- DPP wave64 sum reductions (result broadcast via readlane 63) ----
#define DPPADD(v, ctrl) \
  v += __int_as_float(__builtin_amdgcn_update_dpp(0, __float_as_int(v), ctrl, 0xf, 0xf, false));

__device__ __forceinline__ float wred_b(float v){
  DPPADD(v,0x111) DPPADD(v,0x112) DPPADD(v,0x114) DPPADD(v,0x118)
  DPPADD(v,0x142) DPPADD(v,0x143)
  return __int_as_float(__builtin_amdgcn_readlane(__float_as_int(v), 63));
}
__device__ __forceinline__ void wred3_b(float& v0, float& v1, float& v2){
  DPPADD(v0,0x111) DPPADD(v1,0x111) DPPADD(v2,0x111)
  DPPADD(v0,0x112) DPPADD(v1,0x112) DPPADD(v2,0x112)
  DPPADD(v0,0x114) DPPADD(v1,0x114) DPPADD(v2,0x114)
  DPPADD(v0,0x118) DPPADD(v1,0x118) DPPADD(v2,0x118)
  DPPADD(v0,0x142) DPPADD(v1,0x142) DPPADD(v2,0x142)
  DPPADD(v0,0x143) DPPADD(v1,0x143) DPPADD(v2,0x143)
  v0 = __int_as_float(__builtin_amdgcn_readlane(__float_as_int(v0), 63));
  v1 = __int_as_float(__builtin_amdgcn_readlane(__float_as_int(v1), 63));
  v2 = __int_as_float(__builtin_amdgcn_readlane(__float_as_int(v2), 63));
}

__device__ __forceinline__ float wred(float v){   // shfl version (TLP-rich kernels)
#pragma unroll
  for(int o=32;o;o>>=1) v += __shfl_xor(v, o, 64);
  return v;
}

#define LDS_FENCE() asm volatile("s_waitcnt lgkmcnt(0)" ::: "memory")

// 64-dot via LDS broadcast (k_ux only; TLP hides the latency there)
#define MATVEC64(RES, WROW, HSARR) {                                     \
  float a0=0.f,a1=0.f,a2=0.f,a3=0.f,a4=0.f,a5=0.f,a6=0.f,a7=0.f;         \
  _Pragma("unroll")                                                      \
  for(int j=0;j<64;j+=8){                                                \
    float4 h4 = *(const float4*)(&(HSARR)[j]);                           \
    float4 h5 = *(const float4*)(&(HSARR)[j+4]);                         \
    a0 = fmaf((WROW)[j  ], h4.x, a0); a1 = fmaf((WROW)[j+1], h4.y, a1);  \
    a2 = fmaf((WROW)[j+2], h4.z, a2); a3 = fmaf((WROW)[j+3], h4.w, a3);  \
    a4 = fmaf((WROW)[j+4], h5.x, a4); a5 = fmaf((WROW)[j+5], h5.y, a5);  \
    a6 = fmaf((WROW)[j+6], h5.z, a6); a7 = fmaf((WROW)[j+7], h5.w, a7);  \
  }                                                                      \
  RES = ((a0+a1)+(a2+a3)) + ((a4+a5)+(a6+a7));                           \
}

// 64-dot via v_readlane broadcast (k_rnn): RES_i = sum_j WROW[j]*MV[lane j].
// Pure VALU — no LDS write/fence/read latency on the recurrence critical path.
#define MATVEC_RL(RES, WROW, MV) {                                       \
  float a0=0.f,a1=0.f,a2=0.f,a3=0.f,a4=0.f,a5=0.f,a6=0.f,a7=0.f;         \
  _Pragma("unroll")                                                      \
  for(int j=0;j<64;j+=8){                                                \
    a0 = fmaf(rdlane(MV,j  ), (WROW)[j  ], a0);                          \
    a1 = fmaf(rdlane(MV,j+1), (WROW)[j+1], a1);                          \
    a2 = fmaf(rdlane(MV,j+2), (WROW)[j+2], a2);                          \
    a3 = fmaf(rdlane(MV,j+3), (WROW)[j+3], a3);                          \
    a4 = fmaf(rdlane(MV,j+4), (WROW)[j+4], a4);                          \
    a5 = fmaf(rdlane(MV,j+5), (WROW)[j+5], a5);                          \
    a6 = fmaf(rdlane(MV,j+6), (WROW)[j+6], a6);                          \
    a7 = fmaf(rdlane(MV,j+7), (WROW)[j+7], a7);                          \
  }                                                                      \
  RES = ((a0+a1)+(a2+a3)) + ((a4+a5)+(a6+a7));                           \
}

// ---- kernel 1: ux = mobius_matvec(U, wemb[x]); wux = W.ux; uxn2=||ux||^2; uxb=ux.b ----
__global__ __launch_bounds__(256) void k_ux(const int* __restrict__ x,
    const float* __restrict__ wemb, const float* __restrict__ U,
    const float* __restrict__ Wm, const float* __restrict__ bvec,
    float* __restrict__ ux, float* __restrict__ wux,
    float* __restrict__ uxn2, float* __restrict__ uxb){
  __shared__ __align__(16) float xs[4][64];
  const int wv = threadIdx.x >> 6, lane = threadIdx.x & 63;
  const int bid = blockIdx.x*4 + wv;   // (b*S+s)*4 + h
  const int h = bid & 3;
  const int bs = bid >> 2;
  const int v = x[bs];
  float xi = wemb[(size_t)v*256 + h*64 + lane];
  const float bi = bvec[h*64 + lane];
  xs[wv][lane] = xi;
  LDS_FENCE();
  float mx; MATVEC64(mx, U + h*4096 + lane*64, xs[wv]);
  float t0 = xi*xi, t1 = mx*mx, t2 = mx*bi;
  wred3_b(t0, t1, t2);         // t0=||x||^2, t1=||mx||^2, t2=mx.b
  float xn  = fmaxf(fsqrt(t0), MIN_NORM);
  float mxn = fmaxf(fsqrt(t1), MIN_NORM);
  float scale = fast_tanh(mxn*frcp(xn) * fast_atanh(fminf(xn, 1.f-1e-7f)));
  float sm = scale * frcp(mxn);
  float uxv = sm * mx;                    // mx==0 -> 0
  ux[(size_t)bid*64 + lane] = uxv;
  if(lane==0){
    uxn2[bid] = (t1 > 0.f) ? scale*scale : 0.f;
    uxb[bid]  = sm * t2;
  }
  // second matvec: wux = W . ux  (feeds k_rnn's m-space recurrence)
  xs[wv][lane] = uxv;                     // same-wave DS ops are in-order: safe reuse
  LDS_FENCE();
  float wuv; MATVEC64(wuv, Wm + h*4096 + lane*64, xs[wv]);
  wux[(size_t)bid*64 + lane] = wuv;
}

// ---- kernel 2: sequential Mobius RNN in m-space (m = W.h), readlane matvec ----
// h_{s+1} = al*m + be*u + ga*b ; m_{s+1} = al*(W.m) + be*Wu_s + ga*Wb.
// The loop contains NO LDS/SMEM and NO waitcnt fence: W.m is computed with
// v_readlane broadcasts, so the matvec chain (m only) and the DPP-reduce ->
// transcendental tail chain (m only) interleave freely and join in 3 FMAs.
// (r7 lesson: 2 chains/wave = spills + longer wall; wall = per-step latency.)
#define RNN_STEP(S, USLOT, WUSLOT, Y2V, UBV) {                           \
  const float U_ = USLOT, WU_ = WUSLOT;                                  \
  const float Y2_ = (Y2V), UB_ = (UBV);                                  \
  if((S) < 254){                            /* depth-2 prefetch */       \
    USLOT  = uxp  [(size_t)((S)+2)*256 + lane];                          \
    WUSLOT = wuxp [(size_t)((S)+2)*256 + lane];                          \
  }                                                                      \
  float p0 = m*m, p1 = m*U_, p2 = m*bi;                                  \
  wred3_b(p0, p1, p2);                                                   \
  float r_; MATVEC_RL(r_, wrow, m);         /* no dependency on tail */  \
  float xn  = fmaxf(fsqrt(hh), MIN_NORM);                                \
  float mxn = fmaxf(fsqrt(p0), MIN_NORM);                                \
  float at  = fast_atanh(fminf(xn, 1.f-1e-7f));                          \
  float scale = fast_tanh(mxn*frcp(xn)*at);                              \
  float sm  = scale*frcp(mxn);                                           \
  float wx2 = (p0 > 0.f) ? scale*scale : 0.f;                            \
  float xy  = sm*p1;                                                     \
  float A   = 1.f + 2.f*xy + Y2_;                                        \
  float Bc  = 1.f - wx2;                                                 \
  float iden = frcp(fmaxf(1.f + 2.f*xy + wx2*Y2_, MIN_NORM));            \
  float c1 = A*sm*iden, c2 = Bc*iden;                                    \
  float zz = (A*A*wx2 + 2.f*A*Bc*xy + Bc*Bc*Y2_)*iden*iden;              \
  float zb = (A*sm*p2 + Bc*UB_)*iden;                                    \
  float A2 = 1.f + 2.f*zb + bn2v;                                        \
  float B2 = 1.f - zz;                                                   \
  float iden2 = frcp(fmaxf(1.f + 2.f*zb + zz*bn2v, MIN_NORM));           \
  float e  = A2*iden2, ga = B2*iden2;                                    \
  float al = e*c1, be = e*c2;                                            \
  encp[(size_t)(S)*256 + lane] = fmaf(al, m, fmaf(be, U_, ga*bi));       \
  hh = fmaxf(e*e*zz + 2.f*e*ga*zb + ga*ga*bn2v, 0.f);                    \
  m  = fmaf(al, r_, fmaf(be, WU_, ga*wb));                               \
}

#define RNN_BLOCK(BLK, Y2R, UBR)                                         \
  for(int i=0;i<64;i+=2){                                                \
    RNN_STEP((BLK)*64+i,   uA, wuA, rdlane(Y2R, i),   rdlane(UBR, i));   \
    RNN_STEP((BLK)*64+i+1, uB, wuB, rdlane(Y2R, i+1), rdlane(UBR, i+1)); \
  }

__global__ __launch_bounds__(64) void k_rnn(const float* __restrict__ W,
    const float* __restrict__ bvec, const float* __restrict__ ux,
    const float* __restrict__ wux, const float* __restrict__ uxn2,
    const float* __restrict__ uxb, float* __restrict__ enc){
  const int b = blockIdx.x >> 2, h = blockIdx.x & 3;
  const int lane = threadIdx.x;
  float wrow[64];
  const float* Wp = W + h*4096 + lane*64;
#pragma unroll
  for(int j=0;j<64;j+=4){
    float4 w4 = *(const float4*)(Wp + j);
    wrow[j]=w4.x; wrow[j+1]=w4.y; wrow[j+2]=w4.z; wrow[j+3]=w4.w;
  }
  const float bi = bvec[h*64 + lane];
  // preamble: bn2 = ||b||^2 and wb = W.b (readlane matvec, no LDS)
  const float bn2v = wred_b(bi*bi);
  float wb; MATVEC_RL(wb, wrow, bi);
  const float* uxp   = ux   + (size_t)b*65536 + h*64;   // + s*256 + lane
  const float* wuxp  = wux  + (size_t)b*65536 + h*64;
  const float* uxn2p = uxn2 + (size_t)b*1024  + h;      // + s*4
  const float* uxbp  = uxb  + (size_t)b*1024  + h;
  float* encp        = enc  + (size_t)b*65536 + h*64;
  // scalar tables -> 8 VGPRs: lane ℓ of reg blk holds step blk*64+ℓ
  float y2r0 = uxn2p[(      lane)*4], ubr0 = uxbp[(      lane)*4];
  float y2r1 = uxn2p[( 64 + lane)*4], ubr1 = uxbp[( 64 + lane)*4];
  float y2r2 = uxn2p[(128 + lane)*4], ubr2 = uxbp[(128 + lane)*4];
  float y2r3 = uxn2p[(192 + lane)*4], ubr3 = uxbp[(192 + lane)*4];
  // prefetch s=0 (slot A) and s=1 (slot B)
  float uA  = uxp[lane],         wuA = wuxp[lane];
  float uB  = uxp[256+lane],     wuB = wuxp[256+lane];
  float m = 0.f, hh = 0.f;       // h_0 = 0  ->  m_0 = W.h_0 = 0
  RNN_BLOCK(0, y2r0, ubr0)
  RNN_BLOCK(1, y2r1, ubr1)
  RNN_BLOCK(2, y2r2, ubr2)
  RNN_BLOCK(3, y2r3, ubr3)
}

// ---- row squared-norms: src is [nrows][64] ----
__global__ __launch_bounds__(256) void k_norm2(const float* __restrict__ src,
    float* __restrict__ dst, int nrows){
  const int row = blockIdx.x*4 + (threadIdx.x>>6);
  const int lane = threadIdx.x & 63;
  if(row >= nrows) return;
  float v = src[(size_t)row*64 + lane];
  float n2 = wred(v*v);
  if(lane==0) dst[row] = n2;
}

// acosh(1+y) = log(1 + y + sqrt(y*(2+y))) — cancellation-free, ~13 VALU ops
// vs libm acoshf's ~350-400 (measured: acoshf was 85% of k_dist's VALU issue).
__device__ __forceinline__ float pdist(float dot, float a, float lb){
  float c2  = fmaxf(a + lb - 2.f*dot, 0.f);
  float iden = frcp(fmaxf((1.f-a)*(1.f-lb), MIN_NORM));
  float y   = fmaxf(2.f*c2*iden, 1e-7f);     // == max(arg,1+1e-7) semantics
  return __logf(1.f + y + fsqrt(y*(2.f+y)));
}

// ---- kernel 3: interaction[b,l,s] = sum_h poinc_dist(enc[b,s,h],lab[l,h]) ----
#define LP 68  // padded LDS stride (64 + 4), keeps b128 16B-aligned, kills conflicts
__global__ __launch_bounds__(256) void k_dist(const float* __restrict__ enc,
    const float* __restrict__ lab, const float* __restrict__ an,
    const float* __restrict__ lbn, float* __restrict__ inter){
  __shared__ __align__(16) float eT[4*16*LP];
  __shared__ __align__(16) float lT[4*16*LP];
  const int bs0 = blockIdx.x*64, l0 = blockIdx.y*64;
  const int t = threadIdx.x;
  const int tr = t>>4, tc = t&15;
  const int ldr = t>>2, ldp = t&3;
  float acc[4][4][4];
#pragma unroll
  for(int h=0;h<4;h++)
#pragma unroll
    for(int i=0;i<4;i++)
#pragma unroll
      for(int j=0;j<4;j++) acc[h][i][j]=0.f;

  for(int c=0;c<4;c++){
    if(c) __syncthreads();
#pragma unroll
    for(int h=0;h<4;h++){
      float4 ev = *(const float4*)&enc[(size_t)(bs0+ldr)*256 + h*64 + c*16 + ldp*4];
      float4 lv = *(const float4*)&lab[(size_t)(l0 +ldr)*256 + h*64 + c*16 + ldp*4];
      int base = (h*16 + ldp*4)*LP + ldr;
      eT[base     ] = ev.x; eT[base+  LP] = ev.y; eT[base+2*LP] = ev.z; eT[base+3*LP] = ev.w;
      lT[base     ] = lv.x; lT[base+  LP] = lv.y; lT[base+2*LP] = lv.z; lT[base+3*LP] = lv.w;
    }
    __syncthreads();
#pragma unroll
    for(int dd=0;dd<16;dd++){
#pragma unroll
      for(int h=0;h<4;h++){
        float4 e4 = *(const float4*)&eT[(h*16+dd)*LP + tr*4];
        float4 l4 = *(const float4*)&lT[(h*16+dd)*LP + tc*4];
        float ee[4] = {e4.x,e4.y,e4.z,e4.w};
        float ll[4] = {l4.x,l4.y,l4.z,l4.w};
#pragma unroll
        for(int i=0;i<4;i++)
#pragma unroll
          for(int j=0;j<4;j++)
            acc[h][i][j] = fmaf(ee[i], ll[j], acc[h][i][j]);
      }
    }
  }
  const int b = bs0 >> 8;
#pragma unroll
  for(int i=0;i<4;i++){
    const int bs = bs0 + tr*4 + i;
    const int s  = bs & 255;
    float4 ah = *(const float4*)&an[(size_t)bs*4];
#pragma unroll
    for(int j=0;j<4;j++){
      const int l = l0 + tc*4 + j;
      float4 lb = *(const float4*)&lbn[(size_t)l*4];
      float d = pdist(acc[0][i][j], ah.x, lb.x)
              + pdist(acc[1][i][j], ah.y, lb.y)
              + pdist(acc[2][i][j], ah.z, lb.z)
              + pdist(acc[3][i][j], ah.w, lb.w);
      inter[((size_t)b*1024 + l)*256 + s] = d;
    }
  }
}

// ---- kernel 4: out[b,l] = w2 . relu(w1 @ inter[b,l,:] + b1) + b2 ----
__global__ __launch_bounds__(256) void k_mlp(const float* __restrict__ inter,
    const float* __restrict__ w1, const float* __restrict__ b1,
    const float* __restrict__ w2, const float* __restrict__ b2,
    float* __restrict__ out){
  __shared__ __align__(16) float rows[32*256];
  __shared__ float part[4][16];
  const int b  = blockIdx.x >> 5;
  const int l0 = (blockIdx.x & 31)*32;
  const int t = threadIdx.x;
  const float* ip = inter + ((size_t)b*1024 + l0)*256;
#pragma unroll
  for(int k=0;k<8;k++){
    int idx = k*1024 + t*4;
    *(float4*)&rows[idx] = *(const float4*)&ip[idx];
  }
  __syncthreads();
  const int f = t & 127, g = t >> 7;
  float acc[16];
#pragma unroll
  for(int li=0;li<16;li++) acc[li]=0.f;
  const float* wp = w1 + (size_t)f*256;
  for(int s=0;s<256;s+=4){
    float4 w4 = *(const float4*)&wp[s];
#pragma unroll
    for(int li=0;li<16;li++){
      float4 r4 = *(const float4*)&rows[(g*16+li)*256 + s];
      acc[li] = fmaf(r4.w, w4.w, fmaf(r4.z, w4.z, fmaf(r4.y, w4.y, fmaf(r4.x, w4.x, acc[li]))));
    }
  }
  const float bb1 = b1[f], ww2 = w2[f];
  const int wave = t>>6, lane = t&63;
#pragma unroll
  for(int li=0;li<16;li++){
    float vv = fmaxf(acc[li] + bb1, 0.f) * ww2;
    vv = wred(vv);
    if(lane==0) part[wave][li] = vv;
  }
  __syncthreads();
  if(t < 32){
    int g2 = t>>4, li = t&15;
    out[(size_t)b*1024 + l0 + g2*16 + li] = part[2*g2][li] + part[2*g2+1][li] + b2[0];
  }
}

extern "C" void kernel_launch(void* const* d_in, const int* in_sizes, int n_in,
                              void* d_out, int out_size, void* d_ws, size_t ws_size,
                              hipStream_t stream){
  const int*   x    = (const int*)d_in[0];
  const float* wemb = (const float*)d_in[1];
  const float* lab  = (const float*)d_in[2];
  const float* W    = (const float*)d_in[3];
  const float* U    = (const float*)d_in[4];
  const float* bv   = (const float*)d_in[5];
  const float* w1   = (const float*)d_in[6];
  const float* b1   = (const float*)d_in[7];
  const float* w2   = (const float*)d_in[8];
  const float* b2   = (const float*)d_in[9];
  float* out = (float*)d_out;

  float* ws    = (float*)d_ws;
  float* enc   = ws;                      // 2,097,152 f  [B*S*H][64]
  float* an    = enc + 2097152;           //    32,768 f  [B*S*H]
  float* lbn   = an  + 32768;             //     4,096 f  [L*H]
  float* ux    = lbn + 4096;              // 2,097,152 f  (dead after k_rnn)
  float* uxn2  = ux  + 2097152;           //    32,768 f
  float* uxb   = uxn2 + 32768;            //    32,768 f
  float* wux   = uxb + 32768;             // 2,097,152 f  (dead after k_rnn)
  float* inter = lbn + 4096;              // 8,388,608 f  [B][L][S] (overlaps ux..wux)
  // peak ws use: 2134016 + 8388608 floats ≈ 42.1 MB (unchanged)

  k_ux   <<<8192, 256, 0, stream>>>(x, wemb, U, W, bv, ux, wux, uxn2, uxb);
  k_norm2<<<1024, 256, 0, stream>>>(lab, lbn, 4096);
  k_rnn  <<<128,   64, 0, stream>>>(W, bv, ux, wux, uxn2, uxb, enc);
  k_norm2<<<8192, 256, 0, stream>>>(enc, an, 32768);
  dim3 g3(128, 16);
  k_dist <<<g3,   256, 0, stream>>>(enc, lab, an, lbn, inter);
  k_mlp  <<<1024, 256, 0, stream>>>(inter, w1, b1, w2, b2, out);
}

// Round 9
// 384.644 us; speedup vs baseline: 1.7610x; 1.2194x over previous
//
#include <hip/hip_runtime.h>
#include <math.h>

#define MIN_NORM 1e-15f

// B=32, S=256, V=30000, L=1024, H=4, D=64

// ---- fast scalar helpers ----
__device__ __forceinline__ float frcp(float x){ return __builtin_amdgcn_rcpf(x); }
__device__ __forceinline__ float fsqrt(float x){ return __builtin_amdgcn_sqrtf(x); }
__device__ __forceinline__ float fast_atanh(float x){        // x in [0, 1-1e-7]
  return 0.5f * __logf((1.f + x) * frcp(1.f - x));
}
__device__ __forceinline__ float fast_tanh(float y){         // y >= 0
  float e = __expf(-2.f * y);
  return (1.f - e) * frcp(1.f + e);
}
__device__ __forceinline__ float rdlane(float v, int l){     // imm/uniform lane idx
  return __int_as_float(__builtin_amdgcn_readlane(__float_as_int(v), l));
}

// ---- DPP wave64 sum reductions (result broadcast via readlane 63) ----
#define DPPADD(v, ctrl) \
  v += __int_as_float(__builtin_amdgcn_update_dpp(0, __float_as_int(v), ctrl, 0xf, 0xf, false));

__device__ __forceinline__ float wred_b(float v){
  DPPADD(v,0x111) DPPADD(v,0x112) DPPADD(v,0x114) DPPADD(v,0x118)
  DPPADD(v,0x142) DPPADD(v,0x143)
  return __int_as_float(__builtin_amdgcn_readlane(__float_as_int(v), 63));
}
__device__ __forceinline__ void wred3_b(float& v0, float& v1, float& v2){
  DPPADD(v0,0x111) DPPADD(v1,0x111) DPPADD(v2,0x111)
  DPPADD(v0,0x112) DPPADD(v1,0x112) DPPADD(v2,0x112)
  DPPADD(v0,0x114) DPPADD(v1,0x114) DPPADD(v2,0x114)
  DPPADD(v0,0x118) DPPADD(v1,0x118) DPPADD(v2,0x118)
  DPPADD(v0,0x142) DPPADD(v1,0x142) DPPADD(v2,0x142)
  DPPADD(v0,0x143) DPPADD(v1,0x143) DPPADD(v2,0x143)
  v0 = __int_as_float(__builtin_amdgcn_readlane(__float_as_int(v0), 63));
  v1 = __int_as_float(__builtin_amdgcn_readlane(__float_as_int(v1), 63));
  v2 = __int_as_float(__builtin_amdgcn_readlane(__float_as_int(v2), 63));
}

__device__ __forceinline__ float wred(float v){   // shfl version (TLP-rich kernels)
#pragma unroll
  for(int o=32;o;o>>=1) v += __shfl_xor(v, o, 64);
  return v;
}

#define LDS_FENCE() asm volatile("s_waitcnt lgkmcnt(0)" ::: "memory")

// 64-dot via v_readlane broadcast: RES_i = sum_j WROW[j]*MV[lane j]. Pure VALU.
#define MATVEC_RL(RES, WROW, MV) {                                       \
  float a0=0.f,a1=0.f,a2=0.f,a3=0.f,a4=0.f,a5=0.f,a6=0.f,a7=0.f;         \
  _Pragma("unroll")                                                      \
  for(int j=0;j<64;j+=8){                                                \
    a0 = fmaf(rdlane(MV,j  ), (WROW)[j  ], a0);                          \
    a1 = fmaf(rdlane(MV,j+1), (WROW)[j+1], a1);                          \
    a2 = fmaf(rdlane(MV,j+2), (WROW)[j+2], a2);                          \
    a3 = fmaf(rdlane(MV,j+3), (WROW)[j+3], a3);                          \
    a4 = fmaf(rdlane(MV,j+4), (WROW)[j+4], a4);                          \
    a5 = fmaf(rdlane(MV,j+5), (WROW)[j+5], a5);                          \
    a6 = fmaf(rdlane(MV,j+6), (WROW)[j+6], a6);                          \
    a7 = fmaf(rdlane(MV,j+7), (WROW)[j+7], a7);                          \
  }                                                                      \
  RES = ((a0+a1)+(a2+a3)) + ((a4+a5)+(a6+a7));                           \
}

// dual 64-dot sharing one set of rdlane broadcasts (64 rdlane + 128 FMA)
#define MATVEC_RL2(R1, W1, R2, W2, MV) {                                 \
  float a0=0.f,a1=0.f,a2=0.f,a3=0.f, c0=0.f,c1=0.f,c2=0.f,c3=0.f;        \
  _Pragma("unroll")                                                      \
  for(int j=0;j<64;j+=4){                                                \
    float s0 = rdlane(MV,j  ), s1 = rdlane(MV,j+1);                      \
    float s2 = rdlane(MV,j+2), s3 = rdlane(MV,j+3);                      \
    a0 = fmaf(s0,(W1)[j  ],a0); c0 = fmaf(s0,(W2)[j  ],c0);              \
    a1 = fmaf(s1,(W1)[j+1],a1); c1 = fmaf(s1,(W2)[j+1],c1);              \
    a2 = fmaf(s2,(W1)[j+2],a2); c2 = fmaf(s2,(W2)[j+2],c2);              \
    a3 = fmaf(s3,(W1)[j+3],a3); c3 = fmaf(s3,(W2)[j+3],c3);              \
  }                                                                      \
  R1 = (a0+a1)+(a2+a3); R2 = (c0+c1)+(c2+c3);                            \
}

// ---- kernel 0: WU_h = W_h @ U_h  (4 tiny 64x64x64 GEMMs, runs once) ----
__global__ __launch_bounds__(256) void k_wu(const float* __restrict__ W,
    const float* __restrict__ U, float* __restrict__ WU){
  __shared__ float Ws[64*65];        // pad 65: row-access bank-conflict-free
  __shared__ float Us[64*64];
  const int h = blockIdx.x;
  const int t = threadIdx.x;
#pragma unroll
  for(int k=0;k<16;k+=4){
    float4 w4 = *(const float4*)&W[h*4096 + t*16 + k];
    Ws[(t>>2)*65 + (t&3)*16 + k  ] = w4.x; Ws[(t>>2)*65 + (t&3)*16 + k+1] = w4.y;
    Ws[(t>>2)*65 + (t&3)*16 + k+2] = w4.z; Ws[(t>>2)*65 + (t&3)*16 + k+3] = w4.w;
    *(float4*)&Us[t*16 + k] = *(const float4*)&U[h*4096 + t*16 + k];
  }
  __syncthreads();
  const int i = t>>2, j0 = (t&3)*16;
  float acc[16];
#pragma unroll
  for(int j=0;j<16;j++) acc[j]=0.f;
  for(int k=0;k<64;k++){
    float w = Ws[i*65+k];
#pragma unroll
    for(int j=0;j<16;j++) acc[j] = fmaf(w, Us[k*64+j0+j], acc[j]);
  }
#pragma unroll
  for(int j=0;j<16;j+=4)
    *(float4*)&WU[h*4096 + i*64 + j0 + j] = make_float4(acc[j],acc[j+1],acc[j+2],acc[j+3]);
}

// ---- kernel 1: ux = mobius_matvec(U, wemb[x]); wux = sm*(WU@x); 8 bs per wave ----
// U/WU rows live in VGPRs across 8 matvec pairs (amortizes the 32KB L2 fetch
// that dominated r8's k_ux); x broadcast via rdlane (no LDS/fence); both
// matvecs share rdlane scalars and are independent of the scalar tail.
__global__ __launch_bounds__(256) void k_ux(const int* __restrict__ x,
    const float* __restrict__ wemb, const float* __restrict__ U,
    const float* __restrict__ WU, const float* __restrict__ bvec,
    float* __restrict__ ux, float* __restrict__ wux,
    float* __restrict__ uxn2, float* __restrict__ uxb){
  const int wv = threadIdx.x >> 6, lane = threadIdx.x & 63;
  const int h = blockIdx.x & 3;
  const int bs0 = (blockIdx.x >> 2)*32 + wv*8;    // 8 bs per wave
  float urow[64], wurow[64];
  const float* Up  = U  + h*4096 + lane*64;
  const float* WUp = WU + h*4096 + lane*64;
#pragma unroll
  for(int j=0;j<64;j+=4){
    float4 a = *(const float4*)(Up + j);
    urow[j]=a.x; urow[j+1]=a.y; urow[j+2]=a.z; urow[j+3]=a.w;
    float4 c = *(const float4*)(WUp + j);
    wurow[j]=c.x; wurow[j+1]=c.y; wurow[j+2]=c.z; wurow[j+3]=c.w;
  }
  const float bi = bvec[h*64 + lane];
  int vv[8];
#pragma unroll
  for(int k=0;k<8;k++) vv[k] = x[bs0+k];
  float xv[8];
#pragma unroll
  for(int k=0;k<8;k++) xv[k] = wemb[(size_t)vv[k]*256 + h*64 + lane];
#pragma unroll 2
  for(int k=0;k<8;k++){
    float mx, wmx;
    MATVEC_RL2(mx, urow, wmx, wurow, xv[k]);
    float t0 = xv[k]*xv[k], t1 = mx*mx, t2 = mx*bi;
    wred3_b(t0, t1, t2);       // t0=||x||^2, t1=||mx||^2, t2=mx.b
    float xn  = fmaxf(fsqrt(t0), MIN_NORM);
    float mxn = fmaxf(fsqrt(t1), MIN_NORM);
    float scale = fast_tanh(mxn*frcp(xn) * fast_atanh(fminf(xn, 1.f-1e-7f)));
    float sm = scale * frcp(mxn);
    const int bid = (bs0+k)*4 + h;
    ux [(size_t)bid*64 + lane] = sm * mx;     // mx==0 -> 0
    wux[(size_t)bid*64 + lane] = sm * wmx;    // = sm*(W@(U@x)) up to association
    if(lane==0){
      uxn2[bid] = (t1 > 0.f) ? scale*scale : 0.f;
      uxb[bid]  = sm * t2;
    }
  }
}

// ---- kernel 2: sequential Mobius RNN in m-space (m = W.h), readlane matvec ----
// h_{s+1} = al*m + be*u + ga*b ; m_{s+1} = al*(W.m) + be*Wu_s + ga*Wb.
// Loop has NO LDS/SMEM and NO waitcnt fence (r8 passing version, unchanged).
#define RNN_STEP(S, USLOT, WUSLOT, Y2V, UBV) {                           \
  const float U_ = USLOT, WU_ = WUSLOT;                                  \
  const float Y2_ = (Y2V), UB_ = (UBV);                                  \
  if((S) < 254){                            /* depth-2 prefetch */       \
    USLOT  = uxp  [(size_t)((S)+2)*256 + lane];                          \
    WUSLOT = wuxp [(size_t)((S)+2)*256 + lane];                          \
  }                                                                      \
  float p0 = m*m, p1 = m*U_, p2 = m*bi;                                  \
  wred3_b(p0, p1, p2);                                                   \
  float r_; MATVEC_RL(r_, wrow, m);         /* no dependency on tail */  \
  float xn  = fmaxf(fsqrt(hh), MIN_NORM);                                \
  float mxn = fmaxf(fsqrt(p0), MIN_NORM);                                \
  float at  = fast_atanh(fminf(xn, 1.f-1e-7f));                          \
  float scale = fast_tanh(mxn*frcp(xn)*at);                              \
  float sm  = scale*frcp(mxn);                                           \
  float wx2 = (p0 > 0.f) ? scale*scale : 0.f;                            \
  float xy  = sm*p1;                                                     \
  float A   = 1.f + 2.f*xy + Y2_;                                        \
  float Bc  = 1.f - wx2;                                                 \
  float iden = frcp(fmaxf(1.f + 2.f*xy + wx2*Y2_, MIN_NORM));            \
  float c1 = A*sm*iden, c2 = Bc*iden;                                    \
  float zz = (A*A*wx2 + 2.f*A*Bc*xy + Bc*Bc*Y2_)*iden*iden;              \
  float zb = (A*sm*p2 + Bc*UB_)*iden;                                    \
  float A2 = 1.f + 2.f*zb + bn2v;                                        \
  float B2 = 1.f - zz;                                                   \
  float iden2 = frcp(fmaxf(1.f + 2.f*zb + zz*bn2v, MIN_NORM));           \
  float e  = A2*iden2, ga = B2*iden2;                                    \
  float al = e*c1, be = e*c2;                                            \
  encp[(size_t)(S)*256 + lane] = fmaf(al, m, fmaf(be, U_, ga*bi));       \
  hh = fmaxf(e*e*zz + 2.f*e*ga*zb + ga*ga*bn2v, 0.f);                    \
  m  = fmaf(al, r_, fmaf(be, WU_, ga*wb));                               \
}

#define RNN_BLOCK(BLK, Y2R, UBR)                                         \
  for(int i=0;i<64;i+=2){                                                \
    RNN_STEP((BLK)*64+i,   uA, wuA, rdlane(Y2R, i),   rdlane(UBR, i));   \
    RNN_STEP((BLK)*64+i+1, uB, wuB, rdlane(Y2R, i+1), rdlane(UBR, i+1)); \
  }

__global__ __launch_bounds__(64) void k_rnn(const float* __restrict__ W,
    const float* __restrict__ bvec, const float* __restrict__ ux,
    const float* __restrict__ wux, const float* __restrict__ uxn2,
    const float* __restrict__ uxb, float* __restrict__ enc){
  const int b = blockIdx.x >> 2, h = blockIdx.x & 3;
  const int lane = threadIdx.x;
  float wrow[64];
  const float* Wp = W + h*4096 + lane*64;
#pragma unroll
  for(int j=0;j<64;j+=4){
    float4 w4 = *(const float4*)(Wp + j);
    wrow[j]=w4.x; wrow[j+1]=w4.y; wrow[j+2]=w4.z; wrow[j+3]=w4.w;
  }
  const float bi = bvec[h*64 + lane];
  const float bn2v = wred_b(bi*bi);
  float wb; MATVEC_RL(wb, wrow, bi);
  const float* uxp   = ux   + (size_t)b*65536 + h*64;   // + s*256 + lane
  const float* wuxp  = wux  + (size_t)b*65536 + h*64;
  const float* uxn2p = uxn2 + (size_t)b*1024  + h;      // + s*4
  const float* uxbp  = uxb  + (size_t)b*1024  + h;
  float* encp        = enc  + (size_t)b*65536 + h*64;
  float y2r0 = uxn2p[(      lane)*4], ubr0 = uxbp[(      lane)*4];
  float y2r1 = uxn2p[( 64 + lane)*4], ubr1 = uxbp[( 64 + lane)*4];
  float y2r2 = uxn2p[(128 + lane)*4], ubr2 = uxbp[(128 + lane)*4];
  float y2r3 = uxn2p[(192 + lane)*4], ubr3 = uxbp[(192 + lane)*4];
  float uA  = uxp[lane],         wuA = wuxp[lane];
  float uB  = uxp[256+lane],     wuB = wuxp[256+lane];
  float m = 0.f, hh = 0.f;       // h_0 = 0  ->  m_0 = W.h_0 = 0
  RNN_BLOCK(0, y2r0, ubr0)
  RNN_BLOCK(1, y2r1, ubr1)
  RNN_BLOCK(2, y2r2, ubr2)
  RNN_BLOCK(3, y2r3, ubr3)
}

// ---- row squared-norms: src is [nrows][64] ----
__global__ __launch_bounds__(256) void k_norm2(const float* __restrict__ src,
    float* __restrict__ dst, int nrows){
  const int row = blockIdx.x*4 + (threadIdx.x>>6);
  const int lane = threadIdx.x & 63;
  if(row >= nrows) return;
  float v = src[(size_t)row*64 + lane];
  float n2 = wred(v*v);
  if(lane==0) dst[row] = n2;
}

// acosh(1+y) = log(1 + y + sqrt(y*(2+y))) — cancellation-free, ~13 VALU ops
__device__ __forceinline__ float pdist(float dot, float a, float lb){
  float c2  = fmaxf(a + lb - 2.f*dot, 0.f);
  float iden = frcp(fmaxf((1.f-a)*(1.f-lb), MIN_NORM));
  float y   = fmaxf(2.f*c2*iden, 1e-7f);     // == max(arg,1+1e-7) semantics
  return __logf(1.f + y + fsqrt(y*(2.f+y)));
}

// ---- kernel 3: interaction[b,l,s] = sum_h poinc_dist(enc[b,s,h],lab[l,h]) ----
#define LP 68  // padded LDS stride (64 + 4), keeps b128 16B-aligned, kills conflicts
__global__ __launch_bounds__(256) void k_dist(const float* __restrict__ enc,
    const float* __restrict__ lab, const float* __restrict__ an,
    const float* __restrict__ lbn, float* __restrict__ inter){
  __shared__ __align__(16) float eT[4*16*LP];
  __shared__ __align__(16) float lT[4*16*LP];
  const int bs0 = blockIdx.x*64, l0 = blockIdx.y*64;
  const int t = threadIdx.x;
  const int tr = t>>4, tc = t&15;
  const int ldr = t>>2, ldp = t&3;
  float acc[4][4][4];
#pragma unroll
  for(int h=0;h<4;h++)
#pragma unroll
    for(int i=0;i<4;i++)
#pragma unroll
      for(int j=0;j<4;j++) acc[h][i][j]=0.f;

  for(int c=0;c<4;c++){
    if(c) __syncthreads();
#pragma unroll
    for(int h=0;h<4;h++){
      float4 ev = *(const float4*)&enc[(size_t)(bs0+ldr)*256 + h*64 + c*16 + ldp*4];
      float4 lv = *(const float4*)&lab[(size_t)(l0 +ldr)*256 + h*64 + c*16 + ldp*4];
      int base = (h*16 + ldp*4)*LP + ldr;
      eT[base     ] = ev.x; eT[base+  LP] = ev.y; eT[base+2*LP] = ev.z; eT[base+3*LP] = ev.w;
      lT[base     ] = lv.x; lT[base+  LP] = lv.y; lT[base+2*LP] = lv.z; lT[base+3*LP] = lv.w;
    }
    __syncthreads();
#pragma unroll
    for(int dd=0;dd<16;dd++){
#pragma unroll
      for(int h=0;h<4;h++){
        float4 e4 = *(const float4*)&eT[(h*16+dd)*LP + tr*4];
        float4 l4 = *(const float4*)&lT[(h*16+dd)*LP + tc*4];
        float ee[4] = {e4.x,e4.y,e4.z,e4.w};
        float ll[4] = {l4.x,l4.y,l4.z,l4.w};
#pragma unroll
        for(int i=0;i<4;i++)
#pragma unroll
          for(int j=0;j<4;j++)
            acc[h][i][j] = fmaf(ee[i], ll[j], acc[h][i][j]);
      }
    }
  }
  const int b = bs0 >> 8;
#pragma unroll
  for(int i=0;i<4;i++){
    const int bs = bs0 + tr*4 + i;
    const int s  = bs & 255;
    float4 ah = *(const float4*)&an[(size_t)bs*4];
#pragma unroll
    for(int j=0;j<4;j++){
      const int l = l0 + tc*4 + j;
      float4 lb = *(const float4*)&lbn[(size_t)l*4];
      float d = pdist(acc[0][i][j], ah.x, lb.x)
              + pdist(acc[1][i][j], ah.y, lb.y)
              + pdist(acc[2][i][j], ah.z, lb.z)
              + pdist(acc[3][i][j], ah.w, lb.w);
      inter[((size_t)b*1024 + l)*256 + s] = d;
    }
  }
}

// ---- kernel 4: out[b,l] = w2 . relu(w1 @ inter[b,l,:] + b1) + b2 ----
__global__ __launch_bounds__(256) void k_mlp(const float* __restrict__ inter,
    const float* __restrict__ w1, const float* __restrict__ b1,
    const float* __restrict__ w2, const float* __restrict__ b2,
    float* __restrict__ out){
  __shared__ __align__(16) float rows[32*256];
  __shared__ float part[4][16];
  const int b  = blockIdx.x >> 5;
  const int l0 = (blockIdx.x & 31)*32;
  const int t = threadIdx.x;
  const float* ip = inter + ((size_t)b*1024 + l0)*256;
#pragma unroll
  for(int k=0;k<8;k++){
    int idx = k*1024 + t*4;
    *(float4*)&rows[idx] = *(const float4*)&ip[idx];
  }
  __syncthreads();
  const int f = t & 127, g = t >> 7;
  float acc[16];
#pragma unroll
  for(int li=0;li<16;li++) acc[li]=0.f;
  const float* wp = w1 + (size_t)f*256;
  for(int s=0;s<256;s+=4){
    float4 w4 = *(const float4*)&wp[s];
#pragma unroll
    for(int li=0;li<16;li++){
      float4 r4 = *(const float4*)&rows[(g*16+li)*256 + s];
      acc[li] = fmaf(r4.w, w4.w, fmaf(r4.z, w4.z, fmaf(r4.y, w4.y, fmaf(r4.x, w4.x, acc[li]))));
    }
  }
  const float bb1 = b1[f], ww2 = w2[f];
  const int wave = t>>6, lane = t&63;
#pragma unroll
  for(int li=0;li<16;li++){
    float vv = fmaxf(acc[li] + bb1, 0.f) * ww2;
    vv = wred(vv);
    if(lane==0) part[wave][li] = vv;
  }
  __syncthreads();
  if(t < 32){
    int g2 = t>>4, li = t&15;
    out[(size_t)b*1024 + l0 + g2*16 + li] = part[2*g2][li] + part[2*g2+1][li] + b2[0];
  }
}

extern "C" void kernel_launch(void* const* d_in, const int* in_sizes, int n_in,
                              void* d_out, int out_size, void* d_ws, size_t ws_size,
                              hipStream_t stream){
  const int*   x    = (const int*)d_in[0];
  const float* wemb = (const float*)d_in[1];
  const float* lab  = (const float*)d_in[2];
  const float* W    = (const float*)d_in[3];
  const float* U    = (const float*)d_in[4];
  const float* bv   = (const float*)d_in[5];
  const float* w1   = (const float*)d_in[6];
  const float* b1   = (const float*)d_in[7];
  const float* w2   = (const float*)d_in[8];
  const float* b2   = (const float*)d_in[9];
  float* out = (float*)d_out;

  float* ws    = (float*)d_ws;
  float* enc   = ws;                      // 2,097,152 f  [B*S*H][64]
  float* an    = enc + 2097152;           //    32,768 f  [B*S*H]
  float* lbn   = an  + 32768;             //     4,096 f  [L*H]
  float* ux    = lbn + 4096;              // 2,097,152 f  (dead after k_rnn)
  float* uxn2  = ux  + 2097152;           //    32,768 f
  float* uxb   = uxn2 + 32768;            //    32,768 f
  float* wux   = uxb + 32768;             // 2,097,152 f  (dead after k_rnn)
  float* WU    = wux + 2097152;           //    16,384 f  (dead after k_ux)
  float* inter = lbn + 4096;              // 8,388,608 f  [B][L][S] (overlaps ux..WU)
  // peak ws use: 2134016 + 8388608 floats ≈ 42.1 MB (unchanged)

  k_wu   <<<4,    256, 0, stream>>>(W, U, WU);
  k_ux   <<<1024, 256, 0, stream>>>(x, wemb, U, WU, bv, ux, wux, uxn2, uxb);
  k_norm2<<<1024, 256, 0, stream>>>(lab, lbn, 4096);
  k_rnn  <<<128,   64, 0, stream>>>(W, bv, ux, wux, uxn2, uxb, enc);
  k_norm2<<<8192, 256, 0, stream>>>(enc, an, 32768);
  dim3 g3(128, 16);
  k_dist <<<g3,   256, 0, stream>>>(enc, lab, an, lbn, inter);
  k_mlp  <<<1024, 256, 0, stream>>>(inter, w1, b1, w2, b2, out);
}